// Round 14
// baseline (711.036 us; speedup 1.0000x reference)
//
#include <hip/hip_runtime.h>
#include <hip/hip_bf16.h>
#include <cstdint>

// Problem constants (match setup_inputs)
constexpr int B  = 2;
constexpr int L  = 2048;
constexpr int S  = 2048;
constexpr int DM = 1024;
constexpr int H  = 16;
constexpr int R  = 32;     // rank
constexpr int DH = 64;     // head dim
constexpr int TOPK = 32;
constexpr int SELCAP = 36;
constexpr float SCALE = 0.17677669529663687f; // 1/sqrt(32)

// MEASURED (R4-R13): VGPR cap = LDS-implied occupancy; LICM hoists
// loop-invariant LDS reads -> spill (defeat: opaque-zero asm, R9).
// R13: occupancy 42->63% did NOT help (VALU-work-bound, not TLP-starved)
// -> revert half-split; attack instruction count instead (varying-bit radix).

using short8 = __attribute__((ext_vector_type(8))) short;
using f32x4  = __attribute__((ext_vector_type(4))) float;

__device__ __forceinline__ unsigned short bf16_rne(float x) {
    unsigned int u = __float_as_uint(x);
    unsigned int r = u + 0x7FFFu + ((u >> 16) & 1u);
    return (unsigned short)(r >> 16);
}

// ---------------------------------------------------------------------------
// fp32 GEMM body (R9-proven FMA order; bit-identical outputs).
// AsR = [16][136] floats, WsR = [16][132] floats (LDS-carved).
// ---------------------------------------------------------------------------
__device__ __forceinline__
void qk_gemm_body(const float* __restrict__ A, const float* __restrict__ W,
                  const float* __restrict__ bias, float* __restrict__ C,
                  int M, int N, int K, float outScale, int bx, int by,
                  float* AsR, float* WsR)
{
    const int t  = threadIdx.x;
    const int tx = t & 15;
    const int ty = t >> 4;
    const int m0 = by * 128;
    const int n0 = bx * 128;

    float acc[8][8];
#pragma unroll
    for (int i = 0; i < 8; ++i)
#pragma unroll
        for (int j = 0; j < 8; ++j) acc[i][j] = 0.f;

    for (int kb = 0; kb < K; kb += 16) {
        __syncthreads();
#pragma unroll
        for (int it = 0; it < 2; ++it) {
            int f4  = t + it * 256;
            int row = f4 >> 2;
            int cg  = (f4 & 3) * 4;
            float4 av = *(const float4*)&A[(size_t)(m0 + row) * K + kb + cg];
            AsR[(cg + 0) * 136 + row] = av.x;
            AsR[(cg + 1) * 136 + row] = av.y;
            AsR[(cg + 2) * 136 + row] = av.z;
            AsR[(cg + 3) * 136 + row] = av.w;
        }
#pragma unroll
        for (int it = 0; it < 2; ++it) {
            int f4 = t + it * 256;
            int kk = f4 >> 5;
            int cb = (f4 & 31) * 4;
            *(float4*)&WsR[kk * 132 + cb] = *(const float4*)&W[(size_t)(kb + kk) * N + n0 + cb];
        }
        __syncthreads();
#pragma unroll
        for (int kk = 0; kk < 16; ++kk) {
            float4 a0 = *(const float4*)&AsR[kk * 136 + ty * 8];
            float4 a1 = *(const float4*)&AsR[kk * 136 + ty * 8 + 4];
            float4 w0 = *(const float4*)&WsR[kk * 132 + tx * 8];
            float4 w1 = *(const float4*)&WsR[kk * 132 + tx * 8 + 4];
            float a[8] = {a0.x, a0.y, a0.z, a0.w, a1.x, a1.y, a1.z, a1.w};
            float w[8] = {w0.x, w0.y, w0.z, w0.w, w1.x, w1.y, w1.z, w1.w};
#pragma unroll
            for (int i = 0; i < 8; ++i)
#pragma unroll
                for (int j = 0; j < 8; ++j)
                    acc[i][j] = fmaf(a[i], w[j], acc[i][j]);
        }
    }

    float4 b0 = *(const float4*)&bias[n0 + tx * 8];
    float4 b1 = *(const float4*)&bias[n0 + tx * 8 + 4];
#pragma unroll
    for (int i = 0; i < 8; ++i) {
        float4 o0 = make_float4((acc[i][0] + b0.x) * outScale, (acc[i][1] + b0.y) * outScale,
                                (acc[i][2] + b0.z) * outScale, (acc[i][3] + b0.w) * outScale);
        float4 o1 = make_float4((acc[i][4] + b1.x) * outScale, (acc[i][5] + b1.y) * outScale,
                                (acc[i][6] + b1.z) * outScale, (acc[i][7] + b1.w) * outScale);
        size_t off = (size_t)(m0 + ty * 8 + i) * N + n0 + tx * 8;
        *(float4*)&C[off]     = o0;
        *(float4*)&C[off + 4] = o1;
    }
}

// ---------------------------------------------------------------------------
// Split-bf16 MFMA GEMM body (R11-proven). LDS carved: 4 x 128*56 shorts.
// ---------------------------------------------------------------------------
__device__ __forceinline__
void mfma_gemm_body(const float* __restrict__ A, const unsigned short* __restrict__ Bh,
                    const unsigned short* __restrict__ Bl, const float* __restrict__ bias,
                    float* __restrict__ C, int M, int N, int K, int bx, int by,
                    unsigned short* Ah, unsigned short* Al,
                    unsigned short* Wh, unsigned short* Wl)
{
    constexpr int LDT = 56;
    const int t    = threadIdx.x;
    const int lane = t & 63;
    const int w    = t >> 6;
    const int wr   = w >> 1;
    const int wc   = w & 1;
    const int l15  = lane & 15;
    const int l4   = lane >> 4;
    const int m0   = by * 128;
    const int n0   = bx * 128;

    f32x4 acc[4][4];
#pragma unroll
    for (int m = 0; m < 4; ++m)
#pragma unroll
        for (int n = 0; n < 4; ++n) {
            f32x4 z = {0.f, 0.f, 0.f, 0.f};
            acc[m][n] = z;
        }

#pragma unroll 1
    for (int kb = 0; kb < K; kb += 32) {
        __syncthreads();
#pragma unroll
        for (int it = 0; it < 4; ++it) {
            int f   = t + it * 256;
            int row = f >> 3;
            int kg  = (f & 7) * 4;
            float4 av = *(const float4*)&A[(size_t)(m0 + row) * K + kb + kg];
            ushort4 hv, lv;
            hv.x = bf16_rne(av.x); lv.x = bf16_rne(av.x - __uint_as_float((unsigned int)hv.x << 16));
            hv.y = bf16_rne(av.y); lv.y = bf16_rne(av.y - __uint_as_float((unsigned int)hv.y << 16));
            hv.z = bf16_rne(av.z); lv.z = bf16_rne(av.z - __uint_as_float((unsigned int)hv.z << 16));
            hv.w = bf16_rne(av.w); lv.w = bf16_rne(av.w - __uint_as_float((unsigned int)hv.w << 16));
            *(ushort4*)&Ah[row * LDT + kg] = hv;
            *(ushort4*)&Al[row * LDT + kg] = lv;
            ushort4 bh4 = *(const ushort4*)&Bh[(size_t)(n0 + row) * K + kb + kg];
            ushort4 bl4 = *(const ushort4*)&Bl[(size_t)(n0 + row) * K + kb + kg];
            *(ushort4*)&Wh[row * LDT + kg] = bh4;
            *(ushort4*)&Wl[row * LDT + kg] = bl4;
        }
        __syncthreads();

        short8 ah[4], al[4], bh[4], bl[4];
#pragma unroll
        for (int m = 0; m < 4; ++m) {
            int row = wr * 64 + m * 16 + l15;
            ah[m] = *(short8*)&Ah[row * LDT + l4 * 8];
            al[m] = *(short8*)&Al[row * LDT + l4 * 8];
        }
#pragma unroll
        for (int n = 0; n < 4; ++n) {
            int col = wc * 64 + n * 16 + l15;
            bh[n] = *(short8*)&Wh[col * LDT + l4 * 8];
            bl[n] = *(short8*)&Wl[col * LDT + l4 * 8];
        }
#pragma unroll
        for (int m = 0; m < 4; ++m)
#pragma unroll
            for (int n = 0; n < 4; ++n)
                acc[m][n] = __builtin_amdgcn_mfma_f32_16x16x32_bf16(ah[m], bh[n], acc[m][n], 0, 0, 0);
#pragma unroll
        for (int m = 0; m < 4; ++m)
#pragma unroll
            for (int n = 0; n < 4; ++n)
                acc[m][n] = __builtin_amdgcn_mfma_f32_16x16x32_bf16(ah[m], bl[n], acc[m][n], 0, 0, 0);
#pragma unroll
        for (int m = 0; m < 4; ++m)
#pragma unroll
            for (int n = 0; n < 4; ++n)
                acc[m][n] = __builtin_amdgcn_mfma_f32_16x16x32_bf16(al[m], bh[n], acc[m][n], 0, 0, 0);
    }

#pragma unroll
    for (int m = 0; m < 4; ++m) {
        int row = m0 + wr * 64 + m * 16 + l4 * 4;
#pragma unroll
        for (int n = 0; n < 4; ++n) {
            int col = n0 + wc * 64 + n * 16 + l15;
            float bv = bias[col];
#pragma unroll
            for (int r = 0; r < 4; ++r)
                C[(size_t)(row + r) * N + col] = acc[m][n][r] + bv;
        }
    }
}

// ---------------------------------------------------------------------------
// Merged V-projection (MFMA) + Q/K projection (fp32): even blocks do gemmV
// tiles, odd blocks do qk tiles. Block-uniform branch; LDS union (57344 B).
// MFMA blocks and VALU blocks co-resident per CU -> separate pipes overlap.
// Bodies identical to the proven kernels -> bit-identical outputs.
// ---------------------------------------------------------------------------
__global__ __launch_bounds__(256, 1)
void vproj_qk(const float* __restrict__ v, const unsigned short* __restrict__ WvH,
              const unsigned short* __restrict__ WvL, const float* __restrict__ bv,
              float* __restrict__ Vp,
              const float* __restrict__ q, const float* __restrict__ Wq,
              const float* __restrict__ bq, float* __restrict__ Qp,
              const float* __restrict__ k, const float* __restrict__ Wk,
              const float* __restrict__ bk, float* __restrict__ Kp)
{
    __shared__ __align__(16) char shraw[57344];
    const int bid = blockIdx.x;
    const int idx = bid >> 1;

    if (bid & 1) {
        // qk tile: idx 0..255 -> (bx 0..3, by 0..31, z 0..1)
        const int z  = idx >> 7;
        const int rm = idx & 127;
        const int bx = rm & 3;
        const int by = rm >> 2;
        float* AsR = (float*)shraw;
        float* WsR = AsR + 16 * 136;
        if (z == 0)
            qk_gemm_body(q, Wq, bq, Qp, B * L, H * R, DM, SCALE, bx, by, AsR, WsR);
        else
            qk_gemm_body(k, Wk, bk, Kp, B * L, H * R, DM, 1.0f, bx, by, AsR, WsR);
    } else {
        // gemmV tile: idx 0..255 -> (bx 0..7, by 0..31)
        const int bx = idx & 7;
        const int by = idx >> 3;
        unsigned short* Ah = (unsigned short*)shraw;
        unsigned short* Al = Ah + 128 * 56;
        unsigned short* Wh = Al + 128 * 56;
        unsigned short* Wl = Wh + 128 * 56;
        mfma_gemm_body(v, WvH, WvL, bv, Vp, B * L, DM, DM, bx, by, Ah, Al, Wh, Wl);
    }
}

// ---------------------------------------------------------------------------
// Standalone split-bf16 MFMA GEMM (output projection).
// ---------------------------------------------------------------------------
__global__ __launch_bounds__(256, 1)
void gemm_mfma_split(const float* __restrict__ A, const unsigned short* __restrict__ Bh,
                     const unsigned short* __restrict__ Bl, const float* __restrict__ bias,
                     float* __restrict__ C, int M, int N, int K)
{
    __shared__ __align__(16) unsigned short shm[4 * 128 * 56];
    mfma_gemm_body(A, Bh, Bl, bias, C, M, N, K, blockIdx.x, blockIdx.y,
                   shm, shm + 128 * 56, shm + 2 * 128 * 56, shm + 3 * 128 * 56);
}

// ---------------------------------------------------------------------------
// Dual transpose + split (R12-proven).
// ---------------------------------------------------------------------------
__global__ __launch_bounds__(256)
void transpose_split_dual(const float* __restrict__ Wv_, unsigned short* __restrict__ VhT,
                          unsigned short* __restrict__ VlT,
                          const float* __restrict__ Wo_, unsigned short* __restrict__ OhT,
                          unsigned short* __restrict__ OlT, int N, int K)
{
    const int z = blockIdx.z;
    const float* W = z ? Wo_ : Wv_;
    unsigned short* Th = z ? OhT : VhT;
    unsigned short* Tl = z ? OlT : VlT;

    __shared__ float tile[32][33];
    const int n0 = blockIdx.x * 32;
    const int k0 = blockIdx.y * 32;
    const int tx = threadIdx.x & 31;
    const int ty = threadIdx.x >> 5;

#pragma unroll
    for (int i = ty; i < 32; i += 8)
        tile[i][tx] = W[(size_t)(k0 + i) * N + n0 + tx];
    __syncthreads();
#pragma unroll
    for (int i = ty; i < 32; i += 8) {
        float x = tile[tx][i];
        unsigned short h = bf16_rne(x);
        float hf = __uint_as_float((unsigned int)h << 16);
        unsigned short l = bf16_rne(x - hf);
        Th[(size_t)(n0 + i) * K + k0 + tx] = h;
        Tl[(size_t)(n0 + i) * K + k0 + tx] = l;
    }
}

// ---------------------------------------------------------------------------
// Fused score + exact top-k + softmax + PV gather (R12 structure) with two
// provably-exact VALU trims:
//  (a) varying-bit radix: P init = AND(all u); test only bits of AND^OR.
//      Selection set {u>=P} provably equals full radix (constant-bit
//      decisions are forced; every u contains all AND bits).
//  (b) skip empty j-slots in the exp pass (ballot==0 -> wave-uniform skip).
// Emission order and weight bits unchanged -> bit-identical output.
// ---------------------------------------------------------------------------
__global__ __launch_bounds__(512, 1)
void score_select_gather(const float* __restrict__ Qp, const float* __restrict__ Kp,
                         const float* __restrict__ Vp, float* __restrict__ Oh)
{
    __shared__ float  sclds[8][2048];   // 64 KB
    __shared__ float4 Qlds4[8][8];      // 1 KB

    const int t    = threadIdx.x;
    const int lane = t & 63;
    const int wv   = t >> 6;            // 0..7

    const int wgid = blockIdx.x;
    const int xcd  = wgid & 7;
    const int jj   = wgid >> 3;              // 0..1023
    const int bh   = xcd + 8 * (jj >> 8);    // 0..31
    const int tile = jj & 255;
    const int b    = bh >> 4;
    const int h    = bh & 15;
    const int lbase = tile * 8;

    const float* kbase = Kp + (size_t)b * S * (H * R) + h * R;
    const float* qbase = Qp + (size_t)(b * L + lbase) * (H * R) + h * R;

    if (t < 64) {
        int row = t >> 3, q = t & 7;
        Qlds4[row][q] = *(const float4*)(qbase + (size_t)row * (H * R) + q * 4);
    }
    __syncthreads();

#pragma unroll 1
    for (int c = 0; c < 4; ++c) {
        float4 ka[8];
        const float* kp = kbase + (size_t)(c * 512 + wv * 64 + lane) * (H * R);
#pragma unroll
        for (int q = 0; q < 8; ++q) ka[q] = *(const float4*)(kp + q * 4);

        int zero;
        asm volatile("v_mov_b32 %0, 0" : "=v"(zero));   // anti-LICM (R9)

        const int keyl = c * 512 + wv * 64 + lane;
#pragma unroll
        for (int r = 0; r < 8; ++r) {
            const float4* qrow = Qlds4[r + zero];
            float s = 0.f;
#pragma unroll
            for (int q = 0; q < 8; ++q) {
                float4 qv = qrow[q];
                s = fmaf(qv.x, ka[q].x, s);
                s = fmaf(qv.y, ka[q].y, s);
                s = fmaf(qv.z, ka[q].z, s);
                s = fmaf(qv.w, ka[q].w, s);
            }
            sclds[r][keyl] = s;
        }
    }

    __syncthreads();

    const unsigned long long lanelt = (1ull << lane) - 1ull;
    {
        const int r = wv;

        float sreg[32];
#pragma unroll
        for (int j = 0; j < 32; ++j) sreg[j] = sclds[r][j * 64 + lane];

        // row max (float domain, unchanged)
        float mx = sreg[0];
#pragma unroll
        for (int j = 1; j < 32; ++j) mx = fmaxf(mx, sreg[j]);
#pragma unroll
        for (int off = 32; off >= 1; off >>= 1)
            mx = fmaxf(mx, __shfl_xor(mx, off, 64));

        // in-place sortable conversion + AND/OR accumulation
        unsigned int andu = 0xFFFFFFFFu, oru = 0u;
#pragma unroll
        for (int j = 0; j < 32; ++j) {
            unsigned int bb  = __float_as_uint(sreg[j]);
            unsigned int sgn = (unsigned int)(((int)bb) >> 31);
            unsigned int uu  = bb ^ (sgn | 0x80000000u);
            sreg[j] = __uint_as_float(uu);
            andu &= uu;
            oru  |= uu;
        }
#pragma unroll
        for (int off = 32; off >= 1; off >>= 1) {
            andu &= (unsigned int)__shfl_xor((int)andu, off, 64);
            oru  |= (unsigned int)__shfl_xor((int)oru,  off, 64);
        }

        // varying-bit MSB radix select (exact; see header comment)
        unsigned int P   = andu;
        unsigned int rem = andu ^ oru;
        while (rem) {
            const unsigned int bm = 1u << (31 - __builtin_clz(rem));
            rem &= ~bm;
            const unsigned int test = P | bm;
            int c2 = 0;
#pragma unroll
            for (int j = 0; j < 32; ++j)
                c2 += (int)__popcll(__ballot(__float_as_uint(sreg[j]) >= test));
            if (c2 >= TOPK) {
                P = test;
                if (c2 == TOPK) break;
            }
        }

        // exp pass with empty-slot skip: compact into dead sclds row
        float dsum = 0.f;
        int   base = 0;
#pragma unroll
        for (int j = 0; j < 32; ++j) {
            unsigned int u = __float_as_uint(sreg[j]);
            bool sel = (u >= P);
            unsigned long long m = __ballot(sel);
            if (m) {
                unsigned int sg2  = (unsigned int)(((int)u) >> 31);
                unsigned int mask = 0x80000000u | ~sg2;
                float forig = __uint_as_float(u ^ mask);
                float e = __expf(forig - mx);
                if (sel) {
                    int pos = base + (int)__popcll(m & lanelt);
                    if (pos < SELCAP) {
                        sclds[r][pos]       = e;
                        sclds[r][512 + pos] = __uint_as_float((unsigned int)(j * 64 + lane));
                    }
                }
                dsum += sel ? e : 0.f;
                base += (int)__popcll(m);
            }
        }
#pragma unroll
        for (int off = 32; off >= 1; off >>= 1)
            dsum += __shfl_xor(dsum, off, 64);

        // PV gather (exact R12 summation order)
        const int cn = base < SELCAP ? base : SELCAP;
        const float inv = 1.0f / dsum;
        const float* vb = Vp + (size_t)b * S * DM + h * DH + lane;

        float a0 = 0.f, a1 = 0.f, a2 = 0.f, a3 = 0.f;
        int tt = 0;
        for (; tt + 4 <= cn; tt += 4) {
            int   s0 = (int)__float_as_uint(sclds[r][512 + tt + 0]);
            int   s1 = (int)__float_as_uint(sclds[r][512 + tt + 1]);
            int   s2 = (int)__float_as_uint(sclds[r][512 + tt + 2]);
            int   s3 = (int)__float_as_uint(sclds[r][512 + tt + 3]);
            float w0 = sclds[r][tt + 0], w1 = sclds[r][tt + 1];
            float w2 = sclds[r][tt + 2], w3 = sclds[r][tt + 3];
            a0 = fmaf(w0, vb[(size_t)s0 * DM], a0);
            a1 = fmaf(w1, vb[(size_t)s1 * DM], a1);
            a2 = fmaf(w2, vb[(size_t)s2 * DM], a2);
            a3 = fmaf(w3, vb[(size_t)s3 * DM], a3);
        }
        for (; tt < cn; ++tt) {
            int s0 = (int)__float_as_uint(sclds[r][512 + tt]);
            a0 = fmaf(sclds[r][tt], vb[(size_t)s0 * DM], a0);
        }
        Oh[(size_t)(b * L + lbase + r) * DM + h * DH + lane] = ((a0 + a1) + (a2 + a3)) * inv;
    }
}

// ---------------------------------------------------------------------------
extern "C" void kernel_launch(void* const* d_in, const int* in_sizes, int n_in,
                              void* d_out, int out_size, void* d_ws, size_t ws_size,
                              hipStream_t stream)
{
    const float* q  = (const float*)d_in[0];
    const float* k  = (const float*)d_in[1];
    const float* v  = (const float*)d_in[2];
    const float* Wq = (const float*)d_in[3];
    const float* bq = (const float*)d_in[4];
    const float* Wk = (const float*)d_in[5];
    const float* bk = (const float*)d_in[6];
    const float* Wv = (const float*)d_in[7];
    const float* bv = (const float*)d_in[8];
    const float* Wo = (const float*)d_in[9];
    const float* bo = (const float*)d_in[10];
    // d_in[11] = pos_bias: per-head additive constant -> top-k/softmax invariant -> no-op.

    float* out = (float*)d_out;
    char*  ws  = (char*)d_ws;

    const size_t MB = 1024 * 1024;
    float* Qp = (float*)(ws);             //  8 MiB (pre-scaled Q)
    float* Kp = (float*)(ws + 8  * MB);   //  8 MiB
    float* Vp = (float*)(ws + 16 * MB);   // 16 MiB
    float* Oh = (float*)(ws + 32 * MB);   // 16 MiB
    unsigned short* WvH = (unsigned short*)(ws + 48 * MB);
    unsigned short* WvL = (unsigned short*)(ws + 50 * MB);
    unsigned short* WoH = (unsigned short*)(ws + 52 * MB);
    unsigned short* WoL = (unsigned short*)(ws + 54 * MB);

    const int M = B * L;  // 4096
    dim3 blk(256);

    // 1. both weight transposes
    transpose_split_dual<<<dim3(DM / 32, DM / 32, 2), blk, 0, stream>>>(
        Wv, WvH, WvL, Wo, WoH, WoL, DM, DM);

    // 2. merged V-projection (MFMA) + Q/K projections (fp32), co-scheduled
    vproj_qk<<<dim3(512), blk, 0, stream>>>(
        v, WvH, WvL, bv, Vp, q, Wq, bq, Qp, k, Wk, bk, Kp);

    // 3. fused scores + exact top-k + softmax + PV gather
    score_select_gather<<<dim3(8192), dim3(512), 0, stream>>>(Qp, Kp, Vp, Oh);

    // 4. output projection (split-bf16 MFMA)
    gemm_mfma_split<<<dim3(DM / 128, M / 128), blk, 0, stream>>>(Oh, WoH, WoL, bo, out, M, DM, DM);
}

// Round 15
// 621.385 us; speedup vs baseline: 1.1443x; 1.1443x over previous
//
#include <hip/hip_runtime.h>
#include <hip/hip_bf16.h>
#include <cstdint>

// Problem constants (match setup_inputs)
constexpr int B  = 2;
constexpr int L  = 2048;
constexpr int S  = 2048;
constexpr int DM = 1024;
constexpr int H  = 16;
constexpr int R  = 32;     // rank
constexpr int DH = 64;     // head dim
constexpr int TOPK = 32;
constexpr int SELCAP = 36;
constexpr float SCALE = 0.17677669529663687f; // 1/sqrt(32)

// MEASURED (R4-R14): VGPR cap = LDS-implied occupancy (64KB->2blk->128).
// LICM hoists loop-invariant LDS reads -> spill; defeat w/ opaque-zero asm.
// R13: occupancy is NOT the lever (VALU/stall-bound). R14: radix micro-opts
// and kernel merging both regressed -> reverted to R12 structure.
// R15: K double-buffer now fits (demand ~96 <= 128 post-anti-LICM).

using short8 = __attribute__((ext_vector_type(8))) short;
using f32x4  = __attribute__((ext_vector_type(4))) float;

__device__ __forceinline__ unsigned short bf16_rne(float x) {
    unsigned int u = __float_as_uint(x);
    unsigned int r = u + 0x7FFFu + ((u >> 16) & 1u);
    return (unsigned short)(r >> 16);
}

// ---------------------------------------------------------------------------
// Merged Q/K projection (R12-proven, bit-identical outputs).
// ---------------------------------------------------------------------------
__global__ __launch_bounds__(256, 2)
void qk_proj(const float* __restrict__ Aq, const float* __restrict__ Wq_,
             const float* __restrict__ bq_, float* __restrict__ Cq,
             const float* __restrict__ Ak, const float* __restrict__ Wk_,
             const float* __restrict__ bk_, float* __restrict__ Ck,
             int M, int N, int K)
{
    const int z = blockIdx.z;
    const float* A    = z ? Ak  : Aq;
    const float* W    = z ? Wk_ : Wq_;
    const float* bias = z ? bk_ : bq_;
    float*       C    = z ? Ck  : Cq;
    const float outScale = z ? 1.0f : SCALE;

    __shared__ float As[16][136];
    __shared__ float Ws[16][132];

    const int t  = threadIdx.x;
    const int tx = t & 15;
    const int ty = t >> 4;
    const int m0 = blockIdx.y * 128;
    const int n0 = blockIdx.x * 128;

    float acc[8][8];
#pragma unroll
    for (int i = 0; i < 8; ++i)
#pragma unroll
        for (int j = 0; j < 8; ++j) acc[i][j] = 0.f;

    for (int kb = 0; kb < K; kb += 16) {
        __syncthreads();
#pragma unroll
        for (int it = 0; it < 2; ++it) {
            int f4  = t + it * 256;
            int row = f4 >> 2;
            int cg  = (f4 & 3) * 4;
            float4 av = *(const float4*)&A[(size_t)(m0 + row) * K + kb + cg];
            As[cg + 0][row] = av.x;
            As[cg + 1][row] = av.y;
            As[cg + 2][row] = av.z;
            As[cg + 3][row] = av.w;
        }
#pragma unroll
        for (int it = 0; it < 2; ++it) {
            int f4 = t + it * 256;
            int kk = f4 >> 5;
            int cb = (f4 & 31) * 4;
            *(float4*)&Ws[kk][cb] = *(const float4*)&W[(size_t)(kb + kk) * N + n0 + cb];
        }
        __syncthreads();
#pragma unroll
        for (int kk = 0; kk < 16; ++kk) {
            float4 a0 = *(const float4*)&As[kk][ty * 8];
            float4 a1 = *(const float4*)&As[kk][ty * 8 + 4];
            float4 w0 = *(const float4*)&Ws[kk][tx * 8];
            float4 w1 = *(const float4*)&Ws[kk][tx * 8 + 4];
            float a[8] = {a0.x, a0.y, a0.z, a0.w, a1.x, a1.y, a1.z, a1.w};
            float w[8] = {w0.x, w0.y, w0.z, w0.w, w1.x, w1.y, w1.z, w1.w};
#pragma unroll
            for (int i = 0; i < 8; ++i)
#pragma unroll
                for (int j = 0; j < 8; ++j)
                    acc[i][j] = fmaf(a[i], w[j], acc[i][j]);
        }
    }

    float4 b0 = *(const float4*)&bias[n0 + tx * 8];
    float4 b1 = *(const float4*)&bias[n0 + tx * 8 + 4];
#pragma unroll
    for (int i = 0; i < 8; ++i) {
        float4 o0 = make_float4((acc[i][0] + b0.x) * outScale, (acc[i][1] + b0.y) * outScale,
                                (acc[i][2] + b0.z) * outScale, (acc[i][3] + b0.w) * outScale);
        float4 o1 = make_float4((acc[i][4] + b1.x) * outScale, (acc[i][5] + b1.y) * outScale,
                                (acc[i][6] + b1.z) * outScale, (acc[i][7] + b1.w) * outScale);
        size_t off = (size_t)(m0 + ty * 8 + i) * N + n0 + tx * 8;
        *(float4*)&C[off]     = o0;
        *(float4*)&C[off + 4] = o1;
    }
}

// ---------------------------------------------------------------------------
// Dual transpose + split (R12-proven).
// ---------------------------------------------------------------------------
__global__ __launch_bounds__(256)
void transpose_split_dual(const float* __restrict__ Wv_, unsigned short* __restrict__ VhT,
                          unsigned short* __restrict__ VlT,
                          const float* __restrict__ Wo_, unsigned short* __restrict__ OhT,
                          unsigned short* __restrict__ OlT, int N, int K)
{
    const int z = blockIdx.z;
    const float* W = z ? Wo_ : Wv_;
    unsigned short* Th = z ? OhT : VhT;
    unsigned short* Tl = z ? OlT : VlT;

    __shared__ float tile[32][33];
    const int n0 = blockIdx.x * 32;
    const int k0 = blockIdx.y * 32;
    const int tx = threadIdx.x & 31;
    const int ty = threadIdx.x >> 5;

#pragma unroll
    for (int i = ty; i < 32; i += 8)
        tile[i][tx] = W[(size_t)(k0 + i) * N + n0 + tx];
    __syncthreads();
#pragma unroll
    for (int i = ty; i < 32; i += 8) {
        float x = tile[tx][i];
        unsigned short h = bf16_rne(x);
        float hf = __uint_as_float((unsigned int)h << 16);
        unsigned short l = bf16_rne(x - hf);
        Th[(size_t)(n0 + i) * K + k0 + tx] = h;
        Tl[(size_t)(n0 + i) * K + k0 + tx] = l;
    }
}

// ---------------------------------------------------------------------------
// Split-bf16 MFMA GEMM (R11-proven).
// ---------------------------------------------------------------------------
__global__ __launch_bounds__(256, 1)
void gemm_mfma_split(const float* __restrict__ A, const unsigned short* __restrict__ Bh,
                     const unsigned short* __restrict__ Bl, const float* __restrict__ bias,
                     float* __restrict__ C, int M, int N, int K)
{
    constexpr int LDT = 56;
    __shared__ unsigned short Ah[128 * LDT];
    __shared__ unsigned short Al[128 * LDT];
    __shared__ unsigned short Wh[128 * LDT];
    __shared__ unsigned short Wl[128 * LDT];

    const int t    = threadIdx.x;
    const int lane = t & 63;
    const int w    = t >> 6;
    const int wr   = w >> 1;
    const int wc   = w & 1;
    const int l15  = lane & 15;
    const int l4   = lane >> 4;
    const int m0   = blockIdx.y * 128;
    const int n0   = blockIdx.x * 128;

    f32x4 acc[4][4];
#pragma unroll
    for (int m = 0; m < 4; ++m)
#pragma unroll
        for (int n = 0; n < 4; ++n) {
            f32x4 z = {0.f, 0.f, 0.f, 0.f};
            acc[m][n] = z;
        }

#pragma unroll 1
    for (int kb = 0; kb < K; kb += 32) {
        __syncthreads();
#pragma unroll
        for (int it = 0; it < 4; ++it) {
            int f   = t + it * 256;
            int row = f >> 3;
            int kg  = (f & 7) * 4;
            float4 av = *(const float4*)&A[(size_t)(m0 + row) * K + kb + kg];
            ushort4 hv, lv;
            hv.x = bf16_rne(av.x); lv.x = bf16_rne(av.x - __uint_as_float((unsigned int)hv.x << 16));
            hv.y = bf16_rne(av.y); lv.y = bf16_rne(av.y - __uint_as_float((unsigned int)hv.y << 16));
            hv.z = bf16_rne(av.z); lv.z = bf16_rne(av.z - __uint_as_float((unsigned int)hv.z << 16));
            hv.w = bf16_rne(av.w); lv.w = bf16_rne(av.w - __uint_as_float((unsigned int)hv.w << 16));
            *(ushort4*)&Ah[row * LDT + kg] = hv;
            *(ushort4*)&Al[row * LDT + kg] = lv;
            ushort4 bh4 = *(const ushort4*)&Bh[(size_t)(n0 + row) * K + kb + kg];
            ushort4 bl4 = *(const ushort4*)&Bl[(size_t)(n0 + row) * K + kb + kg];
            *(ushort4*)&Wh[row * LDT + kg] = bh4;
            *(ushort4*)&Wl[row * LDT + kg] = bl4;
        }
        __syncthreads();

        short8 ah[4], al[4], bh[4], bl[4];
#pragma unroll
        for (int m = 0; m < 4; ++m) {
            int row = wr * 64 + m * 16 + l15;
            ah[m] = *(short8*)&Ah[row * LDT + l4 * 8];
            al[m] = *(short8*)&Al[row * LDT + l4 * 8];
        }
#pragma unroll
        for (int n = 0; n < 4; ++n) {
            int col = wc * 64 + n * 16 + l15;
            bh[n] = *(short8*)&Wh[col * LDT + l4 * 8];
            bl[n] = *(short8*)&Wl[col * LDT + l4 * 8];
        }
#pragma unroll
        for (int m = 0; m < 4; ++m)
#pragma unroll
            for (int n = 0; n < 4; ++n)
                acc[m][n] = __builtin_amdgcn_mfma_f32_16x16x32_bf16(ah[m], bh[n], acc[m][n], 0, 0, 0);
#pragma unroll
        for (int m = 0; m < 4; ++m)
#pragma unroll
            for (int n = 0; n < 4; ++n)
                acc[m][n] = __builtin_amdgcn_mfma_f32_16x16x32_bf16(ah[m], bl[n], acc[m][n], 0, 0, 0);
#pragma unroll
        for (int m = 0; m < 4; ++m)
#pragma unroll
            for (int n = 0; n < 4; ++n)
                acc[m][n] = __builtin_amdgcn_mfma_f32_16x16x32_bf16(al[m], bh[n], acc[m][n], 0, 0, 0);
    }

#pragma unroll
    for (int m = 0; m < 4; ++m) {
        int row = m0 + wr * 64 + m * 16 + l4 * 4;
#pragma unroll
        for (int n = 0; n < 4; ++n) {
            int col = n0 + wc * 64 + n * 16 + l15;
            float bv = bias[col];
#pragma unroll
            for (int r = 0; r < 4; ++r)
                C[(size_t)(row + r) * N + col] = acc[m][n][r] + bv;
        }
    }
}

// ---------------------------------------------------------------------------
// Fused score + exact top-k + softmax + PV gather. R12 selection (proven
// fastest). NEW: K chunk DOUBLE-BUFFER (ka/kb) — chunk c+1's global loads
// issue before chunk c's FMAs, hiding L2 latency. Fits the 128-VGPR cap now
// that anti-LICM keeps Q in LDS (demand ~96). FMA order per (row,key)
// identical to R9-R12 -> bit-identical scores -> bit-identical output.
// ---------------------------------------------------------------------------
__global__ __launch_bounds__(512, 1)
void score_select_gather(const float* __restrict__ Qp, const float* __restrict__ Kp,
                         const float* __restrict__ Vp, float* __restrict__ Oh)
{
    __shared__ float  sclds[8][2048];   // 64 KB
    __shared__ float4 Qlds4[8][8];      // 1 KB

    const int t    = threadIdx.x;
    const int lane = t & 63;
    const int wv   = t >> 6;            // 0..7

    const int wgid = blockIdx.x;
    const int xcd  = wgid & 7;
    const int jj   = wgid >> 3;              // 0..1023
    const int bh   = xcd + 8 * (jj >> 8);    // 0..31
    const int tile = jj & 255;
    const int b    = bh >> 4;
    const int h    = bh & 15;
    const int lbase = tile * 8;

    const float* kbase = Kp + (size_t)b * S * (H * R) + h * R;
    const float* qbase = Qp + (size_t)(b * L + lbase) * (H * R) + h * R;

    if (t < 64) {
        int row = t >> 3, q = t & 7;
        Qlds4[row][q] = *(const float4*)(qbase + (size_t)row * (H * R) + q * 4);
    }

    // prefetch chunk 0 (independent of Q staging)
    float4 ka[8], kb[8];
    {
        const float* kp0 = kbase + (size_t)(wv * 64 + lane) * (H * R);
#pragma unroll
        for (int q = 0; q < 8; ++q) ka[q] = *(const float4*)(kp0 + q * 4);
    }
    __syncthreads();   // Qlds4 ready

    auto compute_chunk = [&](const float4 (&kf)[8], int c0) {
        // anti-LICM: opaque zero, redefined per invocation (R9-proven)
        int zero;
        asm volatile("v_mov_b32 %0, 0" : "=v"(zero));
        const int keyl = c0 * 512 + wv * 64 + lane;
#pragma unroll
        for (int r = 0; r < 8; ++r) {
            const float4* qrow = Qlds4[r + zero];
            float s = 0.f;
#pragma unroll
            for (int q = 0; q < 8; ++q) {
                float4 qv = qrow[q];
                s = fmaf(qv.x, kf[q].x, s);
                s = fmaf(qv.y, kf[q].y, s);
                s = fmaf(qv.z, kf[q].z, s);
                s = fmaf(qv.w, kf[q].w, s);
            }
            sclds[r][keyl] = s;
        }
    };

    {   // c=0: prefetch chunk1 -> kb, compute ka
        const float* kp = kbase + (size_t)(512 + wv * 64 + lane) * (H * R);
#pragma unroll
        for (int q = 0; q < 8; ++q) kb[q] = *(const float4*)(kp + q * 4);
        compute_chunk(ka, 0);
    }
    {   // c=1: prefetch chunk2 -> ka, compute kb
        const float* kp = kbase + (size_t)(1024 + wv * 64 + lane) * (H * R);
#pragma unroll
        for (int q = 0; q < 8; ++q) ka[q] = *(const float4*)(kp + q * 4);
        compute_chunk(kb, 1);
    }
    {   // c=2: prefetch chunk3 -> kb, compute ka
        const float* kp = kbase + (size_t)(1536 + wv * 64 + lane) * (H * R);
#pragma unroll
        for (int q = 0; q < 8; ++q) kb[q] = *(const float4*)(kp + q * 4);
        compute_chunk(ka, 2);
    }
    compute_chunk(kb, 3);   // c=3

    __syncthreads();

    const unsigned long long lanelt = (1ull << lane) - 1ull;
    {
        const int r = wv;

        float sreg[32];
#pragma unroll
        for (int j = 0; j < 32; ++j) sreg[j] = sclds[r][j * 64 + lane];

        float mx = sreg[0];
#pragma unroll
        for (int j = 1; j < 32; ++j) mx = fmaxf(mx, sreg[j]);
#pragma unroll
        for (int off = 32; off >= 1; off >>= 1)
            mx = fmaxf(mx, __shfl_xor(mx, off, 64));

#pragma unroll
        for (int j = 0; j < 32; ++j) {
            unsigned int bb  = __float_as_uint(sreg[j]);
            unsigned int sgn = (unsigned int)(((int)bb) >> 31);
            sreg[j] = __uint_as_float(bb ^ (sgn | 0x80000000u));
        }

        unsigned int P = 0;
        for (int bit = 31; bit >= 0; --bit) {
            unsigned int test = P | (1u << bit);
            int c2 = 0;
#pragma unroll
            for (int j = 0; j < 32; ++j)
                c2 += (int)__popcll(__ballot(__float_as_uint(sreg[j]) >= test));
            if (c2 >= TOPK) {
                P = test;
                if (c2 == TOPK) break;
            }
        }

        float dsum = 0.f;
        int   base = 0;
#pragma unroll
        for (int j = 0; j < 32; ++j) {
            unsigned int u = __float_as_uint(sreg[j]);
            bool sel = (u >= P);
            unsigned int sg2  = (unsigned int)(((int)u) >> 31);
            unsigned int mask = 0x80000000u | ~sg2;
            float forig = __uint_as_float(u ^ mask);
            float e = __expf(forig - mx);
            unsigned long long m = __ballot(sel);
            if (sel) {
                int pos = base + (int)__popcll(m & lanelt);
                if (pos < SELCAP) {
                    sclds[r][pos]       = e;
                    sclds[r][512 + pos] = __uint_as_float((unsigned int)(j * 64 + lane));
                }
            }
            dsum += sel ? e : 0.f;
            base += (int)__popcll(m);
        }
#pragma unroll
        for (int off = 32; off >= 1; off >>= 1)
            dsum += __shfl_xor(dsum, off, 64);

        const int cn = base < SELCAP ? base : SELCAP;
        const float inv = 1.0f / dsum;
        const float* vb = Vp + (size_t)b * S * DM + h * DH + lane;

        float a0 = 0.f, a1 = 0.f, a2 = 0.f, a3 = 0.f;
        int tt = 0;
        for (; tt + 4 <= cn; tt += 4) {
            int   s0 = (int)__float_as_uint(sclds[r][512 + tt + 0]);
            int   s1 = (int)__float_as_uint(sclds[r][512 + tt + 1]);
            int   s2 = (int)__float_as_uint(sclds[r][512 + tt + 2]);
            int   s3 = (int)__float_as_uint(sclds[r][512 + tt + 3]);
            float w0 = sclds[r][tt + 0], w1 = sclds[r][tt + 1];
            float w2 = sclds[r][tt + 2], w3 = sclds[r][tt + 3];
            a0 = fmaf(w0, vb[(size_t)s0 * DM], a0);
            a1 = fmaf(w1, vb[(size_t)s1 * DM], a1);
            a2 = fmaf(w2, vb[(size_t)s2 * DM], a2);
            a3 = fmaf(w3, vb[(size_t)s3 * DM], a3);
        }
        for (; tt < cn; ++tt) {
            int s0 = (int)__float_as_uint(sclds[r][512 + tt]);
            a0 = fmaf(sclds[r][tt], vb[(size_t)s0 * DM], a0);
        }
        Oh[(size_t)(b * L + lbase + r) * DM + h * DH + lane] = ((a0 + a1) + (a2 + a3)) * inv;
    }
}

// ---------------------------------------------------------------------------
extern "C" void kernel_launch(void* const* d_in, const int* in_sizes, int n_in,
                              void* d_out, int out_size, void* d_ws, size_t ws_size,
                              hipStream_t stream)
{
    const float* q  = (const float*)d_in[0];
    const float* k  = (const float*)d_in[1];
    const float* v  = (const float*)d_in[2];
    const float* Wq = (const float*)d_in[3];
    const float* bq = (const float*)d_in[4];
    const float* Wk = (const float*)d_in[5];
    const float* bk = (const float*)d_in[6];
    const float* Wv = (const float*)d_in[7];
    const float* bv = (const float*)d_in[8];
    const float* Wo = (const float*)d_in[9];
    const float* bo = (const float*)d_in[10];
    // d_in[11] = pos_bias: per-head additive constant -> top-k/softmax invariant -> no-op.

    float* out = (float*)d_out;
    char*  ws  = (char*)d_ws;

    const size_t MB = 1024 * 1024;
    float* Qp = (float*)(ws);             //  8 MiB (pre-scaled Q)
    float* Kp = (float*)(ws + 8  * MB);   //  8 MiB
    float* Vp = (float*)(ws + 16 * MB);   // 16 MiB
    float* Oh = (float*)(ws + 32 * MB);   // 16 MiB
    unsigned short* WvH = (unsigned short*)(ws + 48 * MB);
    unsigned short* WvL = (unsigned short*)(ws + 50 * MB);
    unsigned short* WoH = (unsigned short*)(ws + 52 * MB);
    unsigned short* WoL = (unsigned short*)(ws + 54 * MB);

    const int M = B * L;  // 4096
    dim3 blk(256);

    transpose_split_dual<<<dim3(DM / 32, DM / 32, 2), blk, 0, stream>>>(
        Wv, WvH, WvL, Wo, WoH, WoL, DM, DM);

    gemm_mfma_split<<<dim3(DM / 128, M / 128), blk, 0, stream>>>(v, WvH, WvL, bv, Vp, M, DM, DM);

    qk_proj<<<dim3((H * R) / 128, M / 128, 2), blk, 0, stream>>>(
        q, Wq, bq, Qp, k, Wk, bk, Kp, M, H * R, DM);

    score_select_gather<<<dim3(8192), dim3(512), 0, stream>>>(Qp, Kp, Vp, Oh);

    gemm_mfma_split<<<dim3(DM / 128, M / 128), blk, 0, stream>>>(Oh, WoH, WoL, bo, out, M, DM, DM);
}